// Round 1
// 131.369 us; speedup vs baseline: 1.2997x; 1.2997x over previous
//
#include <hip/hip_runtime.h>
#include <hip/hip_bf16.h>

// Problem constants (from reference)
#define F        256
#define NNODES   100000
#define NROOTS   8192
#define SAMP     10
#define KDIM     512        // 2*F concat width
#define HOP1ROWS (NROOTS * SAMP)   // 81920

typedef __bf16   bf16x8  __attribute__((ext_vector_type(8)));
typedef unsigned short ushort8 __attribute__((ext_vector_type(8)));
typedef unsigned int   uint4v  __attribute__((ext_vector_type(4)));
typedef float    f32x4   __attribute__((ext_vector_type(4)));

__device__ __forceinline__ unsigned short f2bf(float f) {
    unsigned int u = __builtin_bit_cast(unsigned int, f);
    u += 0x7FFFu + ((u >> 16) & 1u);      // round-to-nearest-even
    return (unsigned short)(u >> 16);
}

// ---------------------------------------------------------------------------
// Kernel 0: convert W1/W2 (f32 [512][256] row-major in,out) to bf16 in
// B-fragment order: frag[((cb*16 + kblk)*64 + lane)*8 + e] = W[k][col]
//   col = cb*16 + (lane&15),  k = kblk*32 + (lane>>4)*8 + e
// so a wave's B-fragment load is one coalesced 16B/lane read.
// ---------------------------------------------------------------------------
__global__ __launch_bounds__(256)
void wconv_kernel(const float* __restrict__ W1, const float* __restrict__ W2,
                  unsigned short* __restrict__ W1f, unsigned short* __restrict__ W2f)
{
    const int id   = blockIdx.x * 256 + threadIdx.x;   // 32768 total
    const int lane = id & 63;
    const int grp  = id >> 6;          // 512 groups
    const int kblk = grp & 15;
    const int cb   = (grp >> 4) & 15;
    const int mat  = grp >> 8;         // 0 -> W1, 1 -> W2
    const float* W = mat ? W2 : W1;
    unsigned short* dst = mat ? W2f : W1f;

    const int col   = cb * 16 + (lane & 15);
    const int kbase = kblk * 32 + (lane >> 4) * 8;
    ushort8 v;
#pragma unroll
    for (int e = 0; e < 8; ++e) v[e] = f2bf(W[(kbase + e) * 256 + col]);
    *(ushort8*)&dst[(((cb * 16 + kblk) * 64) + lane) * 8] = v;
}

// ---------------------------------------------------------------------------
// Kernel 0b: convert feature matrix f32 [100000][256] -> bf16 copy.
// Pure streaming: 102.4 MB read + 51.2 MB write. The bf16 table (51 MB) is
// fully Infinity-Cache resident, halving all downstream gather bytes.
// ---------------------------------------------------------------------------
__global__ __launch_bounds__(256)
void fmconv_kernel(const float* __restrict__ FM, unsigned short* __restrict__ FMb)
{
    const int stride = gridDim.x * 256;
    const int total  = NNODES * F / 8;             // 3,200,000 groups of 8
    for (int i = blockIdx.x * 256 + threadIdx.x; i < total; i += stride) {
        const float4* p = (const float4*)(FM + (size_t)i * 8);
        float4 x = p[0], y = p[1];
        ushort8 v;
        v[0]=f2bf(x.x); v[1]=f2bf(x.y); v[2]=f2bf(x.z); v[3]=f2bf(x.w);
        v[4]=f2bf(y.x); v[5]=f2bf(y.y); v[6]=f2bf(y.z); v[7]=f2bf(y.w);
        *(ushort8*)&FMb[(size_t)i * 8] = v;
    }
}

// ---------------------------------------------------------------------------
// Fused gather + mean + layer-1 GEMM (+ optional group-of-10 mean reduce).
//   row r: xcat[r] = [ G[selfIdx[r]] , mean_k G[nbIdx[r*10+k]] ]  (bf16)
//   H[r]  = relu(xcat[r] @ W1)                                   [256] f32
// GT = unsigned short (bf16 table, fast path) or float (fallback).
// REDUCE=true  (TM=80): out_comb[root*512 + 256 + c] = bf16(mean over 10 rows)
// REDUCE=false (TM=32): out_comb[row*512 + c]        = bf16(H[r][c])
// ---------------------------------------------------------------------------
template <int TM, bool REDUCE, typename GT>
__global__ __launch_bounds__(256)
void hop_kernel(const GT* __restrict__ FMg,
                const int* __restrict__ selfIdx,
                const int* __restrict__ nbIdx,
                const unsigned short* __restrict__ Wfrag,
                unsigned short* __restrict__ outComb)
{
    __shared__ __align__(16) unsigned short A_lds[TM * KDIM];   // bf16 tile, swizzled
    const int t   = threadIdx.x;
    const int bid = blockIdx.x;

    // ---- Phase A: gather self + mean(10 neighbors) into LDS bf16 ----------
    {
        const int rsub = t >> 5;          // 8 rows in flight
        const int c0   = (t & 31) * 8;    // 8 elements per thread per row
#pragma unroll 1
        for (int rr = 0; rr < TM; rr += 8) {
            const int r  = rr + rsub;
            const int rg = bid * TM + r;
            const int self = selfIdx[rg];
            if constexpr (sizeof(GT) == 2) {
                // bf16 gather path: 16B/lane, self row is already bf16 (same
                // RNE bits as the old f2bf(f32) path).
                ushort8 sv = *(const ushort8*)(FMg + (size_t)self * F + c0);
                *(ushort8*)&A_lds[(r * KDIM + c0) ^ ((r & 7) << 3)] = sv;

                float a0=0,a1=0,a2=0,a3=0,a4=0,a5=0,a6=0,a7=0;
#pragma unroll
                for (int k = 0; k < SAMP; ++k) {
                    const int idx = nbIdx[rg * SAMP + k];
                    uint4v u = __builtin_bit_cast(uint4v,
                        *(const ushort8*)(FMg + (size_t)idx * F + c0));
                    a0 += __builtin_bit_cast(float, u[0] << 16);
                    a1 += __builtin_bit_cast(float, u[0] & 0xFFFF0000u);
                    a2 += __builtin_bit_cast(float, u[1] << 16);
                    a3 += __builtin_bit_cast(float, u[1] & 0xFFFF0000u);
                    a4 += __builtin_bit_cast(float, u[2] << 16);
                    a5 += __builtin_bit_cast(float, u[2] & 0xFFFF0000u);
                    a6 += __builtin_bit_cast(float, u[3] << 16);
                    a7 += __builtin_bit_cast(float, u[3] & 0xFFFF0000u);
                }
                ushort8 m;
                m[0]=f2bf(a0*0.1f); m[1]=f2bf(a1*0.1f); m[2]=f2bf(a2*0.1f); m[3]=f2bf(a3*0.1f);
                m[4]=f2bf(a4*0.1f); m[5]=f2bf(a5*0.1f); m[6]=f2bf(a6*0.1f); m[7]=f2bf(a7*0.1f);
                *(ushort8*)&A_lds[(r * KDIM + F + c0) ^ ((r & 7) << 3)] = m;
            } else {
                // f32 fallback path (original)
                const float4* sp = (const float4*)(FMg + (size_t)self * F + c0);
                float4 s0 = sp[0], s1 = sp[1];
                ushort8 v;
                v[0]=f2bf(s0.x); v[1]=f2bf(s0.y); v[2]=f2bf(s0.z); v[3]=f2bf(s0.w);
                v[4]=f2bf(s1.x); v[5]=f2bf(s1.y); v[6]=f2bf(s1.z); v[7]=f2bf(s1.w);
                *(ushort8*)&A_lds[(r * KDIM + c0) ^ ((r & 7) << 3)] = v;

                float a0=0,a1=0,a2=0,a3=0,a4=0,a5=0,a6=0,a7=0;
#pragma unroll
                for (int k = 0; k < SAMP; ++k) {
                    const int idx = nbIdx[rg * SAMP + k];
                    const float4* np_ = (const float4*)(FMg + (size_t)idx * F + c0);
                    float4 n0 = np_[0], n1 = np_[1];
                    a0+=n0.x; a1+=n0.y; a2+=n0.z; a3+=n0.w;
                    a4+=n1.x; a5+=n1.y; a6+=n1.z; a7+=n1.w;
                }
                ushort8 m;
                m[0]=f2bf(a0*0.1f); m[1]=f2bf(a1*0.1f); m[2]=f2bf(a2*0.1f); m[3]=f2bf(a3*0.1f);
                m[4]=f2bf(a4*0.1f); m[5]=f2bf(a5*0.1f); m[6]=f2bf(a6*0.1f); m[7]=f2bf(a7*0.1f);
                *(ushort8*)&A_lds[(r * KDIM + F + c0) ^ ((r & 7) << 3)] = m;
            }
        }
    }
    __syncthreads();

    // ---- Phase B: MFMA GEMM [TM,512] x [512,256] --------------------------
    constexpr int RM = TM / 16;
    const int wv   = t >> 6;          // wave 0..3 owns cols wv*64..wv*64+63
    const int lane = t & 63;
    const int l16  = lane & 15;
    const int koff = (lane >> 4) * 8;

    f32x4 acc[RM][4];
#pragma unroll
    for (int i = 0; i < RM; ++i)
#pragma unroll
        for (int j = 0; j < 4; ++j) acc[i][j] = (f32x4){0.f, 0.f, 0.f, 0.f};

#pragma unroll 4
    for (int kb = 0; kb < 16; ++kb) {
        const int kbase = kb * 32 + koff;
        ushort8 af[RM];
#pragma unroll
        for (int i = 0; i < RM; ++i) {
            const int row = i * 16 + l16;
            af[i] = *(const ushort8*)&A_lds[(row * KDIM + kbase) ^ ((row & 7) << 3)];
        }
#pragma unroll
        for (int j = 0; j < 4; ++j) {
            const int cb = wv * 4 + j;
            ushort8 bf = *(const ushort8*)&Wfrag[(((cb * 16 + kb) * 64) + lane) * 8];
#pragma unroll
            for (int i = 0; i < RM; ++i) {
                acc[i][j] = __builtin_amdgcn_mfma_f32_16x16x32_bf16(
                    __builtin_bit_cast(bf16x8, af[i]),
                    __builtin_bit_cast(bf16x8, bf),
                    acc[i][j], 0, 0, 0);
            }
        }
    }

    // ---- Phase C: epilogue ------------------------------------------------
    if (REDUCE) {
        __syncthreads();                       // all waves done reading A_lds
        float* C_lds = (float*)A_lds;          // reuse as f32 [TM][256]
#pragma unroll
        for (int i = 0; i < RM; ++i)
#pragma unroll
            for (int j = 0; j < 4; ++j) {
                const int col = (wv * 4 + j) * 16 + l16;
#pragma unroll
                for (int rg_ = 0; rg_ < 4; ++rg_) {
                    const int row = i * 16 + (lane >> 4) * 4 + rg_;
                    C_lds[row * 256 + col] = fmaxf(acc[i][j][rg_], 0.f);
                }
            }
        __syncthreads();
        const int c = t;                        // 256 threads == 256 cols
#pragma unroll
        for (int g = 0; g < TM / 10; ++g) {     // 8 roots per block
            float s = 0.f;
#pragma unroll
            for (int j = 0; j < SAMP; ++j) s += C_lds[(g * SAMP + j) * 256 + c];
            outComb[((size_t)(bid * (TM / 10) + g)) * KDIM + F + c] = f2bf(s * 0.1f);
        }
    } else {
#pragma unroll
        for (int i = 0; i < RM; ++i)
#pragma unroll
            for (int j = 0; j < 4; ++j) {
                const int col = (wv * 4 + j) * 16 + l16;
#pragma unroll
                for (int rg_ = 0; rg_ < 4; ++rg_) {
                    const int row = bid * TM + i * 16 + (lane >> 4) * 4 + rg_;
                    outComb[(size_t)row * KDIM + col] = f2bf(fmaxf(acc[i][j][rg_], 0.f));
                }
            }
    }
}

// ---------------------------------------------------------------------------
// Layer-2 GEMM: out = relu(combined[8192,512](bf16) @ W2) -> f32 [8192,256]
// ---------------------------------------------------------------------------
__global__ __launch_bounds__(256)
void gemm2_kernel(const unsigned short* __restrict__ comb,
                  const unsigned short* __restrict__ Wfrag,
                  float* __restrict__ out)
{
    constexpr int TM = 32;
    __shared__ __align__(16) unsigned short B_lds[TM * KDIM];
    const int t   = threadIdx.x;
    const int bid = blockIdx.x;

    // stage 32 contiguous rows (32KB) into swizzled LDS
    for (int i = t; i < TM * KDIM / 8; i += 256) {
        const int row = i >> 6;
        const int c8  = (i & 63) * 8;
        ushort8 v = *(const ushort8*)&comb[((size_t)(bid * TM + row)) * KDIM + c8];
        *(ushort8*)&B_lds[(row * KDIM + c8) ^ ((row & 7) << 3)] = v;
    }
    __syncthreads();

    constexpr int RM = TM / 16;   // 2
    const int wv = t >> 6, lane = t & 63, l16 = lane & 15, koff = (lane >> 4) * 8;
    f32x4 acc[RM][4];
#pragma unroll
    for (int i = 0; i < RM; ++i)
#pragma unroll
        for (int j = 0; j < 4; ++j) acc[i][j] = (f32x4){0.f, 0.f, 0.f, 0.f};

#pragma unroll 4
    for (int kb = 0; kb < 16; ++kb) {
        const int kbase = kb * 32 + koff;
        ushort8 af[RM];
#pragma unroll
        for (int i = 0; i < RM; ++i) {
            const int row = i * 16 + l16;
            af[i] = *(const ushort8*)&B_lds[(row * KDIM + kbase) ^ ((row & 7) << 3)];
        }
#pragma unroll
        for (int j = 0; j < 4; ++j) {
            const int cb = wv * 4 + j;
            ushort8 bf = *(const ushort8*)&Wfrag[(((cb * 16 + kb) * 64) + lane) * 8];
#pragma unroll
            for (int i = 0; i < RM; ++i) {
                acc[i][j] = __builtin_amdgcn_mfma_f32_16x16x32_bf16(
                    __builtin_bit_cast(bf16x8, af[i]),
                    __builtin_bit_cast(bf16x8, bf),
                    acc[i][j], 0, 0, 0);
            }
        }
    }

#pragma unroll
    for (int i = 0; i < RM; ++i)
#pragma unroll
        for (int j = 0; j < 4; ++j) {
            const int col = (wv * 4 + j) * 16 + l16;
#pragma unroll
            for (int rg_ = 0; rg_ < 4; ++rg_) {
                const int row = bid * TM + i * 16 + (lane >> 4) * 4 + rg_;
                out[(size_t)row * 256 + col] = fmaxf(acc[i][j][rg_], 0.f);
            }
        }
}

// ---------------------------------------------------------------------------
extern "C" void kernel_launch(void* const* d_in, const int* in_sizes, int n_in,
                              void* d_out, int out_size, void* d_ws, size_t ws_size,
                              hipStream_t stream)
{
    const int*   forest0 = (const int*)d_in[0];    // [8192]
    const int*   forest1 = (const int*)d_in[1];    // [8192*10]
    const int*   forest2 = (const int*)d_in[2];    // [81920*10]
    const float* FM      = (const float*)d_in[3];  // [100000*256]
    const float* W1      = (const float*)d_in[4];  // [512*256]
    const float* W2      = (const float*)d_in[5];  // [512*256]
    float*       out     = (float*)d_out;          // [8192*256]

    const size_t fmbElems  = (size_t)NNODES * F;                 // 25,600,000
    const size_t wElems    = (size_t)512 * 256;                  // per weight
    const size_t combElems = (size_t)NROOTS * KDIM;              // 4,194,304
    const size_t needBytes = (fmbElems + 2 * wElems + combElems) * sizeof(unsigned short);

    if (ws_size >= needBytes) {
        // fast path: bf16 feature table (51.2 MB, L3-resident) halves gather bytes
        unsigned short* FMb  = (unsigned short*)d_ws;
        unsigned short* W1f  = FMb + fmbElems;
        unsigned short* W2f  = W1f + wElems;
        unsigned short* comb = W2f + wElems;

        fmconv_kernel<<<dim3(2048), dim3(256), 0, stream>>>(FM, FMb);
        wconv_kernel<<<dim3(128), dim3(256), 0, stream>>>(W1, W2, W1f, W2f);
        // hop-1 level: 81920 rows, 80/block (8 whole roots) -> combined[:,256:512]
        hop_kernel<80, true, unsigned short><<<dim3(HOP1ROWS / 80), dim3(256), 0, stream>>>(
            FMb, forest1, forest2, W1f, comb);
        // root level: 8192 rows -> combined[:,0:256]
        hop_kernel<32, false, unsigned short><<<dim3(NROOTS / 32), dim3(256), 0, stream>>>(
            FMb, forest0, forest1, W1f, comb);
        gemm2_kernel<<<dim3(NROOTS / 32), dim3(256), 0, stream>>>(comb, W2f, out);
    } else {
        // fallback: original f32-gather path (~8.6 MB workspace)
        unsigned short* W1f  = (unsigned short*)d_ws;
        unsigned short* W2f  = W1f + wElems;
        unsigned short* comb = W2f + wElems;

        wconv_kernel<<<dim3(128), dim3(256), 0, stream>>>(W1, W2, W1f, W2f);
        hop_kernel<80, true, float><<<dim3(HOP1ROWS / 80), dim3(256), 0, stream>>>(
            FM, forest1, forest2, W1f, comb);
        hop_kernel<32, false, float><<<dim3(NROOTS / 32), dim3(256), 0, stream>>>(
            FM, forest0, forest1, W1f, comb);
        gemm2_kernel<<<dim3(NROOTS / 32), dim3(256), 0, stream>>>(comb, W2f, out);
    }
}